// Round 4
// baseline (194.735 us; speedup 1.0000x reference)
//
#include <hip/hip_runtime.h>
#include <hip/hip_bf16.h>
#include <stdint.h>

#define S_LEN 2304
#define C_DIM 512
#define NH 8
#define HD 64

typedef __attribute__((ext_vector_type(8))) __bf16 bf16x8;
typedef __attribute__((ext_vector_type(4))) float f32x4;
typedef __attribute__((ext_vector_type(16))) float f32x16;
typedef __attribute__((ext_vector_type(8))) unsigned short u16x8;
typedef __attribute__((ext_vector_type(4))) unsigned short u16x4;
typedef __attribute__((ext_vector_type(4))) unsigned int u32x4;

__device__ __forceinline__ unsigned short bf16u(float f) {
  __hip_bfloat16 h = __float2bfloat16(f);
  return __builtin_bit_cast(unsigned short, h);
}

__device__ __forceinline__ void load_lds16(const void* g, void* l) {
  __builtin_amdgcn_global_load_lds(
      (const __attribute__((address_space(1))) void*)g,
      (__attribute__((address_space(3))) void*)l, 16, 0, 0);
}

__device__ __forceinline__ float max3f(float a, float b, float c) {
  float d;
  asm("v_max3_f32 %0, %1, %2, %3" : "=v"(d) : "v"(a), "v"(b), "v"(c));
  return d;
}

// ---------------- GroupNorm stats: one block per (b, group) ----------------
__global__ __launch_bounds__(256) void gn_stats_kernel(const float* __restrict__ x,
                                                       float* __restrict__ stats) {
  const int bg = blockIdx.x;
  const float4* src = (const float4*)(x + (size_t)bg * 36864);
  float s = 0.f, s2 = 0.f;
#pragma unroll
  for (int i = 0; i < 36; ++i) {
    float4 v = src[i * 256 + threadIdx.x];
    s += v.x + v.y + v.z + v.w;
    s2 += v.x * v.x + v.y * v.y + v.z * v.z + v.w * v.w;
  }
#pragma unroll
  for (int off = 1; off < 64; off <<= 1) {
    s += __shfl_xor(s, off);
    s2 += __shfl_xor(s2, off);
  }
  __shared__ float red[8];
  const int wid = threadIdx.x >> 6;
  if ((threadIdx.x & 63) == 0) { red[wid] = s; red[wid + 4] = s2; }
  __syncthreads();
  if (threadIdx.x == 0) {
    float S = red[0] + red[1] + red[2] + red[3];
    float S2 = red[4] + red[5] + red[6] + red[7];
    float mu = S * (1.f / 36864.f);
    float var = S2 * (1.f / 36864.f) - mu * mu;
    stats[bg * 2] = mu;
    stats[bg * 2 + 1] = rsqrtf(var + 1e-5f);
  }
}

// ------- GN normalize + transpose (b,c,s)->(b,s,c), fp32 -> bf16 ----------
__global__ __launch_bounds__(256) void gn_norm_t_kernel(
    const float* __restrict__ x, const float* __restrict__ gamma,
    const float* __restrict__ beta, const float* __restrict__ stats,
    unsigned short* __restrict__ xn) {
  __shared__ float tile[64][68];
  const int s0 = blockIdx.x * 64, c0 = blockIdx.y * 64, b = blockIdx.z;
  const int tid = threadIdx.x;
  {
    const int cl = tid >> 2, sc = (tid & 3) * 16;
    const float* src = x + ((size_t)b * C_DIM + c0 + cl) * S_LEN + s0 + sc;
#pragma unroll
    for (int i = 0; i < 4; ++i)
      *(float4*)&tile[cl][sc + i * 4] = *(const float4*)(src + i * 4);
  }
  __syncthreads();
  const int sl = tid >> 2, cc = (tid & 3) * 16;
  const int g = (c0 + cc) >> 4;
  const float mu = stats[((size_t)b * 32 + g) * 2];
  const float rs = stats[((size_t)b * 32 + g) * 2 + 1];
  u16x8 o0, o1;
#pragma unroll
  for (int j = 0; j < 8; ++j) {
    const int c = c0 + cc + j;
    o0[j] = bf16u((tile[cc + j][sl] - mu) * rs * gamma[c] + beta[c]);
  }
#pragma unroll
  for (int j = 0; j < 8; ++j) {
    const int c = c0 + cc + 8 + j;
    o1[j] = bf16u((tile[cc + 8 + j][sl] - mu) * rs * gamma[c] + beta[c]);
  }
  unsigned short* dst = xn + ((size_t)b * S_LEN + s0 + sl) * C_DIM + c0 + cc;
  *(u16x8*)dst = o0;
  *(u16x8*)(dst + 8) = o1;
}

// --------- weight transpose: w (K,N) fp32 -> wT (N,K) bf16 -----------------
__global__ __launch_bounds__(256) void wt_kernel(const float* __restrict__ w,
                                                 unsigned short* __restrict__ wT,
                                                 int N, int K) {
  __shared__ float tile[64][68];
  const int n0 = blockIdx.x * 64, k0 = blockIdx.y * 64;
  const int tid = threadIdx.x;
  {
    const int kl = tid >> 2, nc = (tid & 3) * 16;
    const float* src = w + (size_t)(k0 + kl) * N + n0 + nc;
#pragma unroll
    for (int i = 0; i < 4; ++i)
      *(float4*)&tile[kl][nc + i * 4] = *(const float4*)(src + i * 4);
  }
  __syncthreads();
  const int nl = tid >> 2, kc = (tid & 3) * 16;
  u16x8 o0, o1;
#pragma unroll
  for (int j = 0; j < 8; ++j) o0[j] = bf16u(tile[kc + j][nl]);
#pragma unroll
  for (int j = 0; j < 8; ++j) o1[j] = bf16u(tile[kc + 8 + j][nl]);
  unsigned short* dst = wT + (size_t)(n0 + nl) * K + k0 + kc;
  *(u16x8*)dst = o0;
  *(u16x8*)(dst + 8) = o1;
}

// ------------- shared 128x128 GEMM mainloop (A:(M,K) B:(N,K), bf16) --------
__device__ __forceinline__ void gemm128_core(const unsigned short* __restrict__ A,
                                             const unsigned short* __restrict__ B,
                                             int K, int m0, int n0, short* lds_a,
                                             short* lds_b, f32x4 (&acc)[4][4]) {
  const int tid = threadIdx.x;
  const int lane = tid & 63, wid = tid >> 6;
  const int wr = wid >> 1, wc = wid & 1;
  const f32x4 fzero = {0.f, 0.f, 0.f, 0.f};
#pragma unroll
  for (int i = 0; i < 4; ++i)
#pragma unroll
    for (int j = 0; j < 4; ++j) acc[i][j] = fzero;
  const int lrow = lane >> 3;
  const int lcol = (lane & 7) * 8;
  for (int kt = 0; kt < K; kt += 64) {
#pragma unroll
    for (int i = 0; i < 4; ++i) {
      const int r0 = (wid * 4 + i) * 8;
      load_lds16((const void*)(A + (size_t)(m0 + r0 + lrow) * K + kt + lcol), lds_a + r0 * 64);
      load_lds16((const void*)(B + (size_t)(n0 + r0 + lrow) * K + kt + lcol), lds_b + r0 * 64);
    }
    __syncthreads();
#pragma unroll
    for (int ks = 0; ks < 2; ++ks) {
      bf16x8 af[4], bfr[4];
#pragma unroll
      for (int mf = 0; mf < 4; ++mf)
        af[mf] = *(const bf16x8*)(lds_a + ((wr * 64 + mf * 16 + (lane & 15)) * 64 +
                                           ks * 32 + (lane >> 4) * 8));
#pragma unroll
      for (int nf = 0; nf < 4; ++nf)
        bfr[nf] = *(const bf16x8*)(lds_b + ((wc * 64 + nf * 16 + (lane & 15)) * 64 +
                                            ks * 32 + (lane >> 4) * 8));
#pragma unroll
      for (int mf = 0; mf < 4; ++mf)
#pragma unroll
        for (int nf = 0; nf < 4; ++nf)
          acc[mf][nf] =
              __builtin_amdgcn_mfma_f32_16x16x32_bf16(af[mf], bfr[nf], acc[mf][nf], 0, 0, 0);
    }
    __syncthreads();
  }
}

// --------------- QKV GEMM: scatter to Q(scaled)/K (bh,s,64), Vt (bh,64,s) --
__global__ __launch_bounds__(256) void qkv_gemm_kernel(
    const unsigned short* __restrict__ xn, const unsigned short* __restrict__ wT,
    const float* __restrict__ bq, unsigned short* __restrict__ Qb,
    unsigned short* __restrict__ Kb, unsigned short* __restrict__ Vt) {
  __shared__ short lds_a[128 * 64];
  __shared__ short lds_b[128 * 64];
  const int b = blockIdx.z;
  const int m0 = blockIdx.x * 128, n0 = blockIdx.y * 128;
  f32x4 acc[4][4];
  gemm128_core(xn + (size_t)b * S_LEN * C_DIM, wT, C_DIM, m0, n0, lds_a, lds_b, acc);
  const int lane = threadIdx.x & 63, wid = threadIdx.x >> 6;
  const int wr = wid >> 1, wc = wid & 1;
#pragma unroll
  for (int mf = 0; mf < 4; ++mf) {
#pragma unroll
    for (int nf = 0; nf < 4; ++nf) {
      const int n = n0 + wc * 64 + nf * 16 + (lane & 15);
      const int part = n >> 9;
      const int h = (n >> 6) & 7;
      const int d = n & 63;
      const float bias = bq[n];
      const int m = m0 + wr * 64 + mf * 16 + (lane >> 4) * 4;
      if (part == 2) {
        u16x4 pk;
#pragma unroll
        for (int r = 0; r < 4; ++r) pk[r] = bf16u(acc[mf][nf][r] + bias);
        *(u16x4*)(Vt + ((size_t)(b * NH + h) * HD + d) * S_LEN + m) = pk;
      } else {
        unsigned short* dst = part == 0 ? Qb : Kb;
        const float sc = part == 0 ? 0.18033688011112042f : 1.0f;  // 0.125*log2(e)
#pragma unroll
        for (int r = 0; r < 4; ++r)
          dst[((size_t)(b * NH + h) * S_LEN + m + r) * HD + d] =
              bf16u((acc[mf][nf][r] + bias) * sc);
      }
    }
  }
}

// ----------------------------- flash attention -----------------------------
// R2 memory structure (Q in LDS, 2x16KB dbuf, 1-deep prefetch, vmcnt 6/5)
// + VALU cuts: ones-MFMA row-sum, v_max3 tree, z16 as MFMA C-init.
#define QBLK 96
__global__ __launch_bounds__(192) void attn_kernel(const unsigned short* __restrict__ Q,
                                                   const unsigned short* __restrict__ K,
                                                   const unsigned short* __restrict__ Vt,
                                                   unsigned short* __restrict__ O) {
  __shared__ __align__(16) char smem[45056];  // Q 12288 | kv0 16384 | kv1 16384
  const int tid = threadIdx.x;
  const int w = tid >> 6, l = tid & 63;
  const int l31 = l & 31, hi = l >> 5;
  const int bh = blockIdx.y, b = bh >> 3, h = bh & 7;
  const int q0 = blockIdx.x * QBLK;

  const char* gQ = (const char*)Q + (size_t)bh * S_LEN * 128;
  const char* gK = (const char*)K + (size_t)bh * S_LEN * 128;
  const char* gV = (const char*)Vt + (size_t)bh * HD * (S_LEN * 2);

  // per-thread KV staging descriptors (chunks 0..511 K, 512..1023 Vt)
  const char* kvp[6];
  unsigned kvadv[6];
  bool kvok[6];
#pragma unroll
  for (int i = 0; i < 6; ++i) {
    const int c = i * 192 + tid;
    kvok[i] = (c < 1024);
    if (c < 512) {
      const int r = c >> 3, ch = c & 7;
      kvp[i] = gK + (size_t)r * 128 + ((ch ^ (r & 7)) << 4);
      kvadv[i] = 64 * 128;
    } else {
      const int c2 = c & 511;
      const int dd = c2 >> 3, ch = c2 & 7;
      kvp[i] = gV + (size_t)dd * (S_LEN * 2) + ((ch ^ (dd & 7)) << 4);
      kvadv[i] = 128;
    }
  }

  auto stage_kv = [&](char* nreg) {
#pragma unroll
    for (int i = 0; i < 6; ++i) {
      if (kvok[i]) {
        load_lds16((const void*)kvp[i], nreg + (i * 192 + w * 64) * 16);
        kvp[i] += kvadv[i];
      }
    }
  };

  // prologue: stage Q (768 chunks) then KV tile 0
#pragma unroll
  for (int i = 0; i < 4; ++i) {
    const int c0 = i * 192 + w * 64;
    const int c = c0 + l;
    const int r = c >> 3, ch = c & 7;
    load_lds16((const void*)(gQ + (size_t)(q0 + r) * 128 + ((ch ^ (r & 7)) << 4)),
               smem + c0 * 16);
  }
  stage_kv(smem + 12288);
  if (w == 0) asm volatile("s_waitcnt vmcnt(6)" ::: "memory");
  else        asm volatile("s_waitcnt vmcnt(5)" ::: "memory");
  __builtin_amdgcn_s_barrier();

  // hoist Q fragments (B-operand: lane holds Q[q=l31][d])
  bf16x8 qf[4];
  {
    const int qrow = w * 32 + l31;
    const int qsw = qrow & 7;
#pragma unroll
    for (int d4 = 0; d4 < 4; ++d4)
      qf[d4] = *(const bf16x8*)(smem + qrow * 128 + (((d4 * 2 + hi) ^ qsw) << 4));
  }

  const u16x8 onesu = {0x3F80, 0x3F80, 0x3F80, 0x3F80, 0x3F80, 0x3F80, 0x3F80, 0x3F80};
  const bf16x8 onesf = __builtin_bit_cast(bf16x8, onesu);
  f32x16 z16;
#pragma unroll
  for (int i = 0; i < 16; ++i) z16[i] = 0.f;

  float m_run = -1e30f;
  f32x16 oac0, oac1, lacc;
#pragma unroll
  for (int i = 0; i < 16; ++i) { oac0[i] = 0.f; oac1[i] = 0.f; lacc[i] = 0.f; }

  for (int kt = 0; kt < 36; ++kt) {
    char* region = smem + 12288 + ((kt & 1) << 14);
    if (kt < 35) {
      stage_kv(smem + 12288 + (((kt + 1) & 1) << 14));
      if (w == 0) asm volatile("s_waitcnt vmcnt(6)" ::: "memory");
      else        asm volatile("s_waitcnt vmcnt(5)" ::: "memory");
    } else {
      asm volatile("s_waitcnt vmcnt(0)" ::: "memory");
    }
    __builtin_amdgcn_s_barrier();

    const char* kreg = region;
    const char* vreg = region + 8192;
#pragma unroll
    for (int sub = 0; sub < 2; ++sub) {
      // ---- S^T = K · Q^T (C-init from persistent zero vector) ----
      const int krow = sub * 32 + l31;
      const int ksw = krow & 7;
      f32x16 st;
      {
        bf16x8 kf = *(const bf16x8*)(kreg + krow * 128 + (((0 + hi) ^ ksw) << 4));
        st = __builtin_amdgcn_mfma_f32_32x32x16_bf16(kf, qf[0], z16, 0, 0, 0);
      }
#pragma unroll
      for (int d4 = 1; d4 < 4; ++d4) {
        bf16x8 kf = *(const bf16x8*)(kreg + krow * 128 + (((d4 * 2 + hi) ^ ksw) << 4));
        st = __builtin_amdgcn_mfma_f32_32x32x16_bf16(kf, qf[d4], st, 0, 0, 0);
      }
      // ---- tile max via v_max3 tree + cross-half swap ----
      float m0 = max3f(st[0], st[1], st[2]);
      float m1 = max3f(st[3], st[4], st[5]);
      float m2 = max3f(st[6], st[7], st[8]);
      float m3 = max3f(st[9], st[10], st[11]);
      float m4 = max3f(st[12], st[13], st[14]);
      float mt = max3f(m0, m1, st[15]);
      float mb = max3f(m2, m3, m4);
      mt = fmaxf(mt, mb);
      {
        float mo = mt;
        asm volatile("v_permlane32_swap_b32 %0, %1" : "+v"(mt), "+v"(mo));
        mt = fmaxf(mt, mo);
      }
      if (__any((mt - m_run) > 8.f)) {  // defer-max THR=8 (log2 domain)
        const float mnew = fmaxf(m_run, mt);
        const float corr = exp2f(m_run - mnew);
#pragma unroll
        for (int i = 0; i < 16; ++i) { oac0[i] *= corr; oac1[i] *= corr; lacc[i] *= corr; }
        m_run = mnew;
      }
      float p[16];
#pragma unroll
      for (int i = 0; i < 16; ++i) p[i] = exp2f(st[i] - m_run);
      // ---- P -> bf16 B-fragments via cvt_pk + permlane32_swap ----
      unsigned int wv[8];
#pragma unroll
      for (int j = 0; j < 8; ++j)
        asm("v_cvt_pk_bf16_f32 %0, %1, %2" : "=v"(wv[j]) : "v"(p[2 * j]), "v"(p[2 * j + 1]));
      asm volatile("v_permlane32_swap_b32 %0, %1" : "+v"(wv[0]), "+v"(wv[2]));
      asm volatile("v_permlane32_swap_b32 %0, %1" : "+v"(wv[1]), "+v"(wv[3]));
      asm volatile("v_permlane32_swap_b32 %0, %1" : "+v"(wv[4]), "+v"(wv[6]));
      asm volatile("v_permlane32_swap_b32 %0, %1" : "+v"(wv[5]), "+v"(wv[7]));
      u32x4 pw0 = {wv[0], wv[1], wv[2], wv[3]};
      u32x4 pw1 = {wv[4], wv[5], wv[6], wv[7]};
      bf16x8 pf0 = __builtin_bit_cast(bf16x8, pw0);
      bf16x8 pf1 = __builtin_bit_cast(bf16x8, pw1);
      // ---- l accumulation via ones-A MFMA (replaces sum tree) ----
      lacc = __builtin_amdgcn_mfma_f32_32x32x16_bf16(onesf, pf0, lacc, 0, 0, 0);
      lacc = __builtin_amdgcn_mfma_f32_32x32x16_bf16(onesf, pf1, lacc, 0, 0, 0);
      // ---- O^T += V^T · P^T ----
      {
        const int vrow = l31;
        const int vsw = vrow & 7;
        bf16x8 vf0 = *(const bf16x8*)(vreg + vrow * 128 + (((sub * 4 + 0 + hi) ^ vsw) << 4));
        oac0 = __builtin_amdgcn_mfma_f32_32x32x16_bf16(vf0, pf0, oac0, 0, 0, 0);
        bf16x8 vf1 = *(const bf16x8*)(vreg + vrow * 128 + (((sub * 4 + 2 + hi) ^ vsw) << 4));
        oac0 = __builtin_amdgcn_mfma_f32_32x32x16_bf16(vf1, pf1, oac0, 0, 0, 0);
      }
      {
        const int vrow = 32 + l31;
        const int vsw = vrow & 7;
        bf16x8 vf0 = *(const bf16x8*)(vreg + vrow * 128 + (((sub * 4 + 0 + hi) ^ vsw) << 4));
        oac1 = __builtin_amdgcn_mfma_f32_32x32x16_bf16(vf0, pf0, oac1, 0, 0, 0);
        bf16x8 vf1 = *(const bf16x8*)(vreg + vrow * 128 + (((sub * 4 + 2 + hi) ^ vsw) << 4));
        oac1 = __builtin_amdgcn_mfma_f32_32x32x16_bf16(vf1, pf1, oac1, 0, 0, 0);
      }
    }
    __builtin_amdgcn_s_barrier();
  }

  // ---- normalize, transpose via LDS, coalesced store to ao (s, c) ----
  __syncthreads();
  const float inv = 1.f / lacc[0];
  unsigned short* ob = (unsigned short*)smem;  // [96][72]
  const int qrow = w * 32 + l31;
#pragma unroll
  for (int g = 0; g < 4; ++g) {
    u16x4 pk;
#pragma unroll
    for (int r = 0; r < 4; ++r) pk[r] = bf16u(oac0[g * 4 + r] * inv);
    *(u16x4*)(ob + qrow * 72 + (g * 8 + hi * 4)) = pk;
  }
#pragma unroll
  for (int g = 0; g < 4; ++g) {
    u16x4 pk;
#pragma unroll
    for (int r = 0; r < 4; ++r) pk[r] = bf16u(oac1[g * 4 + r] * inv);
    *(u16x4*)(ob + qrow * 72 + (32 + g * 8 + hi * 4)) = pk;
  }
  __syncthreads();
#pragma unroll
  for (int i = 0; i < 4; ++i) {
    const int c = i * 192 + tid;
    const int row = c >> 3, c8 = (c & 7) * 8;
    u16x8 v = *(const u16x8*)(ob + row * 72 + c8);
    *(u16x8*)(O + ((size_t)b * S_LEN + q0 + row) * C_DIM + h * HD + c8) = v;
  }
}

// ------------- proj GEMM (M=c_out, N=s) + bias + residual, fp32 out --------
__global__ __launch_bounds__(256) void proj_gemm_kernel(
    const unsigned short* __restrict__ wT, const unsigned short* __restrict__ ao,
    const float* __restrict__ bp, const float* __restrict__ x, float* __restrict__ out) {
  __shared__ short lds_a[128 * 64];
  __shared__ short lds_b[128 * 64];
  const int b = blockIdx.z;
  const int m0 = blockIdx.x * 128, n0 = blockIdx.y * 128;
  f32x4 acc[4][4];
  gemm128_core(wT, ao + (size_t)b * S_LEN * C_DIM, C_DIM, m0, n0, lds_a, lds_b, acc);
  const int lane = threadIdx.x & 63, wid = threadIdx.x >> 6;
  const int wr = wid >> 1, wc = wid & 1;
#pragma unroll
  for (int mf = 0; mf < 4; ++mf) {
#pragma unroll
    for (int nf = 0; nf < 4; ++nf) {
      const int n = n0 + wc * 64 + nf * 16 + (lane & 15);
#pragma unroll
      for (int r = 0; r < 4; ++r) {
        const int m = m0 + wr * 64 + mf * 16 + (lane >> 4) * 4 + r;
        const size_t idx = ((size_t)b * C_DIM + m) * S_LEN + n;
        out[idx] = x[idx] + acc[mf][nf][r] + bp[m];
      }
    }
  }
}

extern "C" void kernel_launch(void* const* d_in, const int* in_sizes, int n_in,
                              void* d_out, int out_size, void* d_ws, size_t ws_size,
                              hipStream_t stream) {
  const float* x = (const float*)d_in[0];
  const float* gamma = (const float*)d_in[1];
  const float* beta = (const float*)d_in[2];
  const float* w_qkv = (const float*)d_in[3];
  const float* b_qkv = (const float*)d_in[4];
  const float* w_proj = (const float*)d_in[5];
  const float* b_proj = (const float*)d_in[6];
  float* out = (float*)d_out;

  char* ws = (char*)d_ws;
  float* stats = (float*)ws;                                   // 1 KB
  unsigned short* xn = (unsigned short*)(ws + 1024);           // 9437184 B
  unsigned short* wqkvT = (unsigned short*)(ws + 9438208);     // 1572864 B
  unsigned short* wprojT = (unsigned short*)(ws + 11011072);   // 524288 B
  unsigned short* Qb = (unsigned short*)(ws + 11535360);       // 9437184 B
  unsigned short* Kb = (unsigned short*)(ws + 20972544);       // 9437184 B
  unsigned short* Vt = (unsigned short*)(ws + 30409728);       // 9437184 B
  unsigned short* ao = (unsigned short*)(ws + 39846912);       // 9437184 B

  hipLaunchKernelGGL(gn_stats_kernel, dim3(128), dim3(256), 0, stream, x, stats);
  hipLaunchKernelGGL(wt_kernel, dim3(24, 8), dim3(256), 0, stream, w_qkv, wqkvT, 3 * C_DIM, C_DIM);
  hipLaunchKernelGGL(wt_kernel, dim3(8, 8), dim3(256), 0, stream, w_proj, wprojT, C_DIM, C_DIM);
  hipLaunchKernelGGL(gn_norm_t_kernel, dim3(36, 8, 4), dim3(256), 0, stream, x, gamma, beta, stats, xn);
  hipLaunchKernelGGL(qkv_gemm_kernel, dim3(18, 12, 4), dim3(256), 0, stream, xn, wqkvT, b_qkv, Qb, Kb, Vt);
  hipLaunchKernelGGL(attn_kernel, dim3(24, 32), dim3(192), 0, stream, Qb, Kb, Vt, ao);
  hipLaunchKernelGGL(proj_gemm_kernel, dim3(4, 18, 4), dim3(256), 0, stream, wprojT, ao, b_proj, x, out);
}

// Round 5
// 192.276 us; speedup vs baseline: 1.0128x; 1.0128x over previous
//
#include <hip/hip_runtime.h>
#include <hip/hip_bf16.h>
#include <stdint.h>

#define S_LEN 2304
#define C_DIM 512
#define NH 8
#define HD 64

typedef __attribute__((ext_vector_type(8))) __bf16 bf16x8;
typedef __attribute__((ext_vector_type(4))) float f32x4;
typedef __attribute__((ext_vector_type(16))) float f32x16;
typedef __attribute__((ext_vector_type(8))) unsigned short u16x8;
typedef __attribute__((ext_vector_type(4))) unsigned short u16x4;
typedef __attribute__((ext_vector_type(4))) unsigned int u32x4;

__device__ __forceinline__ unsigned short bf16u(float f) {
  __hip_bfloat16 h = __float2bfloat16(f);
  return __builtin_bit_cast(unsigned short, h);
}

__device__ __forceinline__ void load_lds16(const void* g, void* l) {
  __builtin_amdgcn_global_load_lds(
      (const __attribute__((address_space(1))) void*)g,
      (__attribute__((address_space(3))) void*)l, 16, 0, 0);
}

// ---------------- GroupNorm stats: one block per (b, group) ----------------
__global__ __launch_bounds__(256) void gn_stats_kernel(const float* __restrict__ x,
                                                       float* __restrict__ stats) {
  const int bg = blockIdx.x;
  const float4* src = (const float4*)(x + (size_t)bg * 36864);
  float s = 0.f, s2 = 0.f;
#pragma unroll
  for (int i = 0; i < 36; ++i) {
    float4 v = src[i * 256 + threadIdx.x];
    s += v.x + v.y + v.z + v.w;
    s2 += v.x * v.x + v.y * v.y + v.z * v.z + v.w * v.w;
  }
#pragma unroll
  for (int off = 1; off < 64; off <<= 1) {
    s += __shfl_xor(s, off);
    s2 += __shfl_xor(s2, off);
  }
  __shared__ float red[8];
  const int wid = threadIdx.x >> 6;
  if ((threadIdx.x & 63) == 0) { red[wid] = s; red[wid + 4] = s2; }
  __syncthreads();
  if (threadIdx.x == 0) {
    float S = red[0] + red[1] + red[2] + red[3];
    float S2 = red[4] + red[5] + red[6] + red[7];
    float mu = S * (1.f / 36864.f);
    float var = S2 * (1.f / 36864.f) - mu * mu;
    stats[bg * 2] = mu;
    stats[bg * 2 + 1] = rsqrtf(var + 1e-5f);
  }
}

// ------- GN normalize + transpose (b,c,s)->(b,s,c), fp32 -> bf16 ----------
__global__ __launch_bounds__(256) void gn_norm_t_kernel(
    const float* __restrict__ x, const float* __restrict__ gamma,
    const float* __restrict__ beta, const float* __restrict__ stats,
    unsigned short* __restrict__ xn) {
  __shared__ float tile[64][68];
  const int s0 = blockIdx.x * 64, c0 = blockIdx.y * 64, b = blockIdx.z;
  const int tid = threadIdx.x;
  {
    const int cl = tid >> 2, sc = (tid & 3) * 16;
    const float* src = x + ((size_t)b * C_DIM + c0 + cl) * S_LEN + s0 + sc;
#pragma unroll
    for (int i = 0; i < 4; ++i)
      *(float4*)&tile[cl][sc + i * 4] = *(const float4*)(src + i * 4);
  }
  __syncthreads();
  const int sl = tid >> 2, cc = (tid & 3) * 16;
  const int g = (c0 + cc) >> 4;
  const float mu = stats[((size_t)b * 32 + g) * 2];
  const float rs = stats[((size_t)b * 32 + g) * 2 + 1];
  u16x8 o0, o1;
#pragma unroll
  for (int j = 0; j < 8; ++j) {
    const int c = c0 + cc + j;
    o0[j] = bf16u((tile[cc + j][sl] - mu) * rs * gamma[c] + beta[c]);
  }
#pragma unroll
  for (int j = 0; j < 8; ++j) {
    const int c = c0 + cc + 8 + j;
    o1[j] = bf16u((tile[cc + 8 + j][sl] - mu) * rs * gamma[c] + beta[c]);
  }
  unsigned short* dst = xn + ((size_t)b * S_LEN + s0 + sl) * C_DIM + c0 + cc;
  *(u16x8*)dst = o0;
  *(u16x8*)(dst + 8) = o1;
}

// --------- weight transpose: w (K,N) fp32 -> wT (N,K) bf16 -----------------
__global__ __launch_bounds__(256) void wt_kernel(const float* __restrict__ w,
                                                 unsigned short* __restrict__ wT,
                                                 int N, int K) {
  __shared__ float tile[64][68];
  const int n0 = blockIdx.x * 64, k0 = blockIdx.y * 64;
  const int tid = threadIdx.x;
  {
    const int kl = tid >> 2, nc = (tid & 3) * 16;
    const float* src = w + (size_t)(k0 + kl) * N + n0 + nc;
#pragma unroll
    for (int i = 0; i < 4; ++i)
      *(float4*)&tile[kl][nc + i * 4] = *(const float4*)(src + i * 4);
  }
  __syncthreads();
  const int nl = tid >> 2, kc = (tid & 3) * 16;
  u16x8 o0, o1;
#pragma unroll
  for (int j = 0; j < 8; ++j) o0[j] = bf16u(tile[kc + j][nl]);
#pragma unroll
  for (int j = 0; j < 8; ++j) o1[j] = bf16u(tile[kc + 8 + j][nl]);
  unsigned short* dst = wT + (size_t)(n0 + nl) * K + k0 + kc;
  *(u16x8*)dst = o0;
  *(u16x8*)(dst + 8) = o1;
}

// ------------- shared 128x128 GEMM mainloop (A:(M,K) B:(N,K), bf16) --------
__device__ __forceinline__ void gemm128_core(const unsigned short* __restrict__ A,
                                             const unsigned short* __restrict__ B,
                                             int K, int m0, int n0, short* lds_a,
                                             short* lds_b, f32x4 (&acc)[4][4]) {
  const int tid = threadIdx.x;
  const int lane = tid & 63, wid = tid >> 6;
  const int wr = wid >> 1, wc = wid & 1;
  const f32x4 fzero = {0.f, 0.f, 0.f, 0.f};
#pragma unroll
  for (int i = 0; i < 4; ++i)
#pragma unroll
    for (int j = 0; j < 4; ++j) acc[i][j] = fzero;
  const int lrow = lane >> 3;
  const int lcol = (lane & 7) * 8;
  for (int kt = 0; kt < K; kt += 64) {
#pragma unroll
    for (int i = 0; i < 4; ++i) {
      const int r0 = (wid * 4 + i) * 8;
      load_lds16((const void*)(A + (size_t)(m0 + r0 + lrow) * K + kt + lcol), lds_a + r0 * 64);
      load_lds16((const void*)(B + (size_t)(n0 + r0 + lrow) * K + kt + lcol), lds_b + r0 * 64);
    }
    __syncthreads();
#pragma unroll
    for (int ks = 0; ks < 2; ++ks) {
      bf16x8 af[4], bfr[4];
#pragma unroll
      for (int mf = 0; mf < 4; ++mf)
        af[mf] = *(const bf16x8*)(lds_a + ((wr * 64 + mf * 16 + (lane & 15)) * 64 +
                                           ks * 32 + (lane >> 4) * 8));
#pragma unroll
      for (int nf = 0; nf < 4; ++nf)
        bfr[nf] = *(const bf16x8*)(lds_b + ((wc * 64 + nf * 16 + (lane & 15)) * 64 +
                                            ks * 32 + (lane >> 4) * 8));
#pragma unroll
      for (int mf = 0; mf < 4; ++mf)
#pragma unroll
        for (int nf = 0; nf < 4; ++nf)
          acc[mf][nf] =
              __builtin_amdgcn_mfma_f32_16x16x32_bf16(af[mf], bfr[nf], acc[mf][nf], 0, 0, 0);
    }
    __syncthreads();
  }
}

// --------------- QKV GEMM: scatter to Q(scaled)/K (bh,s,64), Vt (bh,64,s) --
__global__ __launch_bounds__(256) void qkv_gemm_kernel(
    const unsigned short* __restrict__ xn, const unsigned short* __restrict__ wT,
    const float* __restrict__ bq, unsigned short* __restrict__ Qb,
    unsigned short* __restrict__ Kb, unsigned short* __restrict__ Vt) {
  __shared__ short lds_a[128 * 64];
  __shared__ short lds_b[128 * 64];
  const int b = blockIdx.z;
  const int m0 = blockIdx.x * 128, n0 = blockIdx.y * 128;
  f32x4 acc[4][4];
  gemm128_core(xn + (size_t)b * S_LEN * C_DIM, wT, C_DIM, m0, n0, lds_a, lds_b, acc);
  const int lane = threadIdx.x & 63, wid = threadIdx.x >> 6;
  const int wr = wid >> 1, wc = wid & 1;
#pragma unroll
  for (int mf = 0; mf < 4; ++mf) {
#pragma unroll
    for (int nf = 0; nf < 4; ++nf) {
      const int n = n0 + wc * 64 + nf * 16 + (lane & 15);
      const int part = n >> 9;
      const int h = (n >> 6) & 7;
      const int d = n & 63;
      const float bias = bq[n];
      const int m = m0 + wr * 64 + mf * 16 + (lane >> 4) * 4;
      if (part == 2) {
        u16x4 pk;
#pragma unroll
        for (int r = 0; r < 4; ++r) pk[r] = bf16u(acc[mf][nf][r] + bias);
        *(u16x4*)(Vt + ((size_t)(b * NH + h) * HD + d) * S_LEN + m) = pk;
      } else {
        unsigned short* dst = part == 0 ? Qb : Kb;
        const float sc = part == 0 ? 0.18033688011112042f : 1.0f;  // 0.125*log2(e)
#pragma unroll
        for (int r = 0; r < 4; ++r)
          dst[((size_t)(b * NH + h) * S_LEN + m + r) * HD + d] =
              bf16u((acc[mf][nf][r] + bias) * sc);
      }
    }
  }
}

// ----------------------------- flash attention -----------------------------
// R2 structure (Q in LDS, 2x16KB dbuf, vmcnt 6/5) + sub0/sub1 software
// pipeline (both QK chains issued first; sm1 VALU overlaps PV0 MFMA)
// + XCD-aware block remap (all q-tiles of a (b,h) on one XCD's L2).
#define QBLK 96
__global__ __launch_bounds__(192) void attn_kernel(const unsigned short* __restrict__ Q,
                                                   const unsigned short* __restrict__ K,
                                                   const unsigned short* __restrict__ Vt,
                                                   unsigned short* __restrict__ O) {
  __shared__ __align__(16) char smem[45056];  // Q 12288 | kv0 16384 | kv1 16384
  const int tid = threadIdx.x;
  const int w = tid >> 6, l = tid & 63;
  const int l31 = l & 31, hi = l >> 5;
  // XCD-aware remap: consecutive dispatch ids round-robin XCDs; give each XCD
  // 4 heads x all 24 q-tiles so KV stays in its 4MB L2.
  const int L = blockIdx.y * 24 + blockIdx.x;
  const int xcd = L & 7, j = L >> 3;
  const int bh = xcd * 4 + j / 24;
  const int qt = j % 24;
  const int b = bh >> 3, h = bh & 7;
  const int q0 = qt * QBLK;

  const char* gQ = (const char*)Q + (size_t)bh * S_LEN * 128;
  const char* gK = (const char*)K + (size_t)bh * S_LEN * 128;
  const char* gV = (const char*)Vt + (size_t)bh * HD * (S_LEN * 2);

  // per-thread KV staging descriptors (chunks 0..511 K, 512..1023 Vt)
  const char* kvp[6];
  unsigned kvadv[6];
  bool kvok[6];
#pragma unroll
  for (int i = 0; i < 6; ++i) {
    const int c = i * 192 + tid;
    kvok[i] = (c < 1024);
    if (c < 512) {
      const int r = c >> 3, ch = c & 7;
      kvp[i] = gK + (size_t)r * 128 + ((ch ^ (r & 7)) << 4);
      kvadv[i] = 64 * 128;
    } else {
      const int c2 = c & 511;
      const int dd = c2 >> 3, ch = c2 & 7;
      kvp[i] = gV + (size_t)dd * (S_LEN * 2) + ((ch ^ (dd & 7)) << 4);
      kvadv[i] = 128;
    }
  }

  auto stage_kv = [&](char* nreg) {
#pragma unroll
    for (int i = 0; i < 6; ++i) {
      if (kvok[i]) {
        load_lds16((const void*)kvp[i], nreg + (i * 192 + w * 64) * 16);
        kvp[i] += kvadv[i];
      }
    }
  };

  // prologue: stage Q (768 chunks) then KV tile 0
#pragma unroll
  for (int i = 0; i < 4; ++i) {
    const int c0 = i * 192 + w * 64;
    const int c = c0 + l;
    const int r = c >> 3, ch = c & 7;
    load_lds16((const void*)(gQ + (size_t)(q0 + r) * 128 + ((ch ^ (r & 7)) << 4)),
               smem + c0 * 16);
  }
  stage_kv(smem + 12288);
  if (w == 0) asm volatile("s_waitcnt vmcnt(6)" ::: "memory");
  else        asm volatile("s_waitcnt vmcnt(5)" ::: "memory");
  __builtin_amdgcn_s_barrier();

  // hoist Q fragments (B-operand: lane holds Q[q=l31][d])
  bf16x8 qf[4];
  {
    const int qrow = w * 32 + l31;
    const int qsw = qrow & 7;
#pragma unroll
    for (int d4 = 0; d4 < 4; ++d4)
      qf[d4] = *(const bf16x8*)(smem + qrow * 128 + (((d4 * 2 + hi) ^ qsw) << 4));
  }

  float m_run = -1e30f, lsum = 0.f;
  f32x16 oac0, oac1;
#pragma unroll
  for (int i = 0; i < 16; ++i) { oac0[i] = 0.f; oac1[i] = 0.f; }

  for (int kt = 0; kt < 36; ++kt) {
    char* region = smem + 12288 + ((kt & 1) << 14);
    if (kt < 35) {
      stage_kv(smem + 12288 + (((kt + 1) & 1) << 14));
      if (w == 0) asm volatile("s_waitcnt vmcnt(6)" ::: "memory");
      else        asm volatile("s_waitcnt vmcnt(5)" ::: "memory");
    } else {
      asm volatile("s_waitcnt vmcnt(0)" ::: "memory");
    }
    __builtin_amdgcn_s_barrier();

    const char* kreg = region;
    const char* vreg = region + 8192;

    // ---- both QK^T chains first (independent; latency overlaps) ----
    f32x16 st0, st1;
#pragma unroll
    for (int i = 0; i < 16; ++i) { st0[i] = 0.f; st1[i] = 0.f; }
    {
      const int kr0 = l31, sw0 = kr0 & 7;
#pragma unroll
      for (int d4 = 0; d4 < 4; ++d4) {
        bf16x8 kf = *(const bf16x8*)(kreg + kr0 * 128 + (((d4 * 2 + hi) ^ sw0) << 4));
        st0 = __builtin_amdgcn_mfma_f32_32x32x16_bf16(kf, qf[d4], st0, 0, 0, 0);
      }
      const int kr1 = 32 + l31, sw1 = kr1 & 7;
#pragma unroll
      for (int d4 = 0; d4 < 4; ++d4) {
        bf16x8 kf = *(const bf16x8*)(kreg + kr1 * 128 + (((d4 * 2 + hi) ^ sw1) << 4));
        st1 = __builtin_amdgcn_mfma_f32_32x32x16_bf16(kf, qf[d4], st1, 0, 0, 0);
      }
    }

    // ---- softmax + PV per sub; sm(sub1) VALU overlaps PV(sub0) MFMA ----
    auto smpv = [&](f32x16& st, int sub) {
      float t8[8];
#pragma unroll
      for (int i = 0; i < 8; ++i) t8[i] = fmaxf(st[2 * i], st[2 * i + 1]);
#pragma unroll
      for (int i = 0; i < 4; ++i) t8[i] = fmaxf(t8[i], t8[i + 4]);
      float mt = fmaxf(fmaxf(t8[0], t8[1]), fmaxf(t8[2], t8[3]));
      {
        float mo = mt;
        asm volatile("v_permlane32_swap_b32 %0, %1" : "+v"(mt), "+v"(mo));
        mt = fmaxf(mt, mo);
      }
      if (__any((mt - m_run) > 8.f)) {  // defer-max THR=8 (log2 domain)
        const float mnew = fmaxf(m_run, mt);
        const float corr = exp2f(m_run - mnew);
#pragma unroll
        for (int i = 0; i < 16; ++i) { oac0[i] *= corr; oac1[i] *= corr; }
        lsum *= corr;
        m_run = mnew;
      }
      float p[16];
#pragma unroll
      for (int i = 0; i < 16; ++i) p[i] = exp2f(st[i] - m_run);
      float a8[8];
#pragma unroll
      for (int i = 0; i < 8; ++i) a8[i] = p[2 * i] + p[2 * i + 1];
#pragma unroll
      for (int i = 0; i < 4; ++i) a8[i] += a8[i + 4];
      float rs = (a8[0] + a8[1]) + (a8[2] + a8[3]);
      float rsc = rs;
      asm volatile("v_permlane32_swap_b32 %0, %1" : "+v"(rs), "+v"(rsc));
      lsum += rs + rsc;
      unsigned int wv[8];
#pragma unroll
      for (int jj = 0; jj < 8; ++jj)
        asm("v_cvt_pk_bf16_f32 %0, %1, %2" : "=v"(wv[jj]) : "v"(p[2 * jj]), "v"(p[2 * jj + 1]));
      asm volatile("v_permlane32_swap_b32 %0, %1" : "+v"(wv[0]), "+v"(wv[2]));
      asm volatile("v_permlane32_swap_b32 %0, %1" : "+v"(wv[1]), "+v"(wv[3]));
      asm volatile("v_permlane32_swap_b32 %0, %1" : "+v"(wv[4]), "+v"(wv[6]));
      asm volatile("v_permlane32_swap_b32 %0, %1" : "+v"(wv[5]), "+v"(wv[7]));
      u32x4 pw0 = {wv[0], wv[1], wv[2], wv[3]};
      u32x4 pw1 = {wv[4], wv[5], wv[6], wv[7]};
      bf16x8 pf0 = __builtin_bit_cast(bf16x8, pw0);
      bf16x8 pf1 = __builtin_bit_cast(bf16x8, pw1);
      {
        const int vrow = l31;
        const int vsw = vrow & 7;
        bf16x8 vf0 = *(const bf16x8*)(vreg + vrow * 128 + (((sub * 4 + 0 + hi) ^ vsw) << 4));
        oac0 = __builtin_amdgcn_mfma_f32_32x32x16_bf16(vf0, pf0, oac0, 0, 0, 0);
        bf16x8 vf1 = *(const bf16x8*)(vreg + vrow * 128 + (((sub * 4 + 2 + hi) ^ vsw) << 4));
        oac0 = __builtin_amdgcn_mfma_f32_32x32x16_bf16(vf1, pf1, oac0, 0, 0, 0);
      }
      {
        const int vrow = 32 + l31;
        const int vsw = vrow & 7;
        bf16x8 vf0 = *(const bf16x8*)(vreg + vrow * 128 + (((sub * 4 + 0 + hi) ^ vsw) << 4));
        oac1 = __builtin_amdgcn_mfma_f32_32x32x16_bf16(vf0, pf0, oac1, 0, 0, 0);
        bf16x8 vf1 = *(const bf16x8*)(vreg + vrow * 128 + (((sub * 4 + 2 + hi) ^ vsw) << 4));
        oac1 = __builtin_amdgcn_mfma_f32_32x32x16_bf16(vf1, pf1, oac1, 0, 0, 0);
      }
    };
    smpv(st0, 0);
    smpv(st1, 1);

    __builtin_amdgcn_s_barrier();
  }

  // ---- normalize, transpose via LDS, coalesced store to ao (s, c) ----
  __syncthreads();
  const float inv = 1.f / lsum;
  unsigned short* ob = (unsigned short*)smem;  // [96][72]
  const int qrow = w * 32 + l31;
#pragma unroll
  for (int g = 0; g < 4; ++g) {
    u16x4 pk;
#pragma unroll
    for (int r = 0; r < 4; ++r) pk[r] = bf16u(oac0[g * 4 + r] * inv);
    *(u16x4*)(ob + qrow * 72 + (g * 8 + hi * 4)) = pk;
  }
#pragma unroll
  for (int g = 0; g < 4; ++g) {
    u16x4 pk;
#pragma unroll
    for (int r = 0; r < 4; ++r) pk[r] = bf16u(oac1[g * 4 + r] * inv);
    *(u16x4*)(ob + qrow * 72 + (32 + g * 8 + hi * 4)) = pk;
  }
  __syncthreads();
#pragma unroll
  for (int i = 0; i < 4; ++i) {
    const int c = i * 192 + tid;
    const int row = c >> 3, c8 = (c & 7) * 8;
    u16x8 v = *(const u16x8*)(ob + row * 72 + c8);
    *(u16x8*)(O + ((size_t)b * S_LEN + q0 + row) * C_DIM + h * HD + c8) = v;
  }
}

// ------------- proj GEMM (M=c_out, N=s) + bias + residual, fp32 out --------
__global__ __launch_bounds__(256) void proj_gemm_kernel(
    const unsigned short* __restrict__ wT, const unsigned short* __restrict__ ao,
    const float* __restrict__ bp, const float* __restrict__ x, float* __restrict__ out) {
  __shared__ short lds_a[128 * 64];
  __shared__ short lds_b[128 * 64];
  const int b = blockIdx.z;
  const int m0 = blockIdx.x * 128, n0 = blockIdx.y * 128;
  f32x4 acc[4][4];
  gemm128_core(wT, ao + (size_t)b * S_LEN * C_DIM, C_DIM, m0, n0, lds_a, lds_b, acc);
  const int lane = threadIdx.x & 63, wid = threadIdx.x >> 6;
  const int wr = wid >> 1, wc = wid & 1;
#pragma unroll
  for (int mf = 0; mf < 4; ++mf) {
#pragma unroll
    for (int nf = 0; nf < 4; ++nf) {
      const int n = n0 + wc * 64 + nf * 16 + (lane & 15);
#pragma unroll
      for (int r = 0; r < 4; ++r) {
        const int m = m0 + wr * 64 + mf * 16 + (lane >> 4) * 4 + r;
        const size_t idx = ((size_t)b * C_DIM + m) * S_LEN + n;
        out[idx] = x[idx] + acc[mf][nf][r] + bp[m];
      }
    }
  }
}

extern "C" void kernel_launch(void* const* d_in, const int* in_sizes, int n_in,
                              void* d_out, int out_size, void* d_ws, size_t ws_size,
                              hipStream_t stream) {
  const float* x = (const float*)d_in[0];
  const float* gamma = (const float*)d_in[1];
  const float* beta = (const float*)d_in[2];
  const float* w_qkv = (const float*)d_in[3];
  const float* b_qkv = (const float*)d_in[4];
  const float* w_proj = (const float*)d_in[5];
  const float* b_proj = (const float*)d_in[6];
  float* out = (float*)d_out;

  char* ws = (char*)d_ws;
  float* stats = (float*)ws;                                   // 1 KB
  unsigned short* xn = (unsigned short*)(ws + 1024);           // 9437184 B
  unsigned short* wqkvT = (unsigned short*)(ws + 9438208);     // 1572864 B
  unsigned short* wprojT = (unsigned short*)(ws + 11011072);   // 524288 B
  unsigned short* Qb = (unsigned short*)(ws + 11535360);       // 9437184 B
  unsigned short* Kb = (unsigned short*)(ws + 20972544);       // 9437184 B
  unsigned short* Vt = (unsigned short*)(ws + 30409728);       // 9437184 B
  unsigned short* ao = (unsigned short*)(ws + 39846912);       // 9437184 B

  hipLaunchKernelGGL(gn_stats_kernel, dim3(128), dim3(256), 0, stream, x, stats);
  hipLaunchKernelGGL(wt_kernel, dim3(24, 8), dim3(256), 0, stream, w_qkv, wqkvT, 3 * C_DIM, C_DIM);
  hipLaunchKernelGGL(wt_kernel, dim3(8, 8), dim3(256), 0, stream, w_proj, wprojT, C_DIM, C_DIM);
  hipLaunchKernelGGL(gn_norm_t_kernel, dim3(36, 8, 4), dim3(256), 0, stream, x, gamma, beta, stats, xn);
  hipLaunchKernelGGL(qkv_gemm_kernel, dim3(18, 12, 4), dim3(256), 0, stream, xn, wqkvT, b_qkv, Qb, Kb, Vt);
  hipLaunchKernelGGL(attn_kernel, dim3(24, 32), dim3(192), 0, stream, Qb, Kb, Vt, ao);
  hipLaunchKernelGGL(proj_gemm_kernel, dim3(4, 18, 4), dim3(256), 0, stream, wprojT, ao, b_proj, x, out);
}

// Round 7
// 162.913 us; speedup vs baseline: 1.1953x; 1.1802x over previous
//
#include <hip/hip_runtime.h>
#include <hip/hip_bf16.h>
#include <stdint.h>

#define S_LEN 2304
#define C_DIM 512
#define NH 8
#define HD 64

typedef __attribute__((ext_vector_type(8))) __bf16 bf16x8;
typedef __attribute__((ext_vector_type(4))) float f32x4;
typedef __attribute__((ext_vector_type(16))) float f32x16;
typedef __attribute__((ext_vector_type(8))) unsigned short u16x8;
typedef __attribute__((ext_vector_type(4))) unsigned short u16x4;
typedef __attribute__((ext_vector_type(4))) unsigned int u32x4;

__device__ __forceinline__ unsigned short bf16u(float f) {
  __hip_bfloat16 h = __float2bfloat16(f);
  return __builtin_bit_cast(unsigned short, h);
}

__device__ __forceinline__ void load_lds16(const void* g, void* l) {
  __builtin_amdgcn_global_load_lds(
      (const __attribute__((address_space(1))) void*)g,
      (__attribute__((address_space(3))) void*)l, 16, 0, 0);
}

// ---------------- GroupNorm stats: one block per (b, group) ----------------
__global__ __launch_bounds__(256) void gn_stats_kernel(const float* __restrict__ x,
                                                       float* __restrict__ stats) {
  const int bg = blockIdx.x;
  const float4* src = (const float4*)(x + (size_t)bg * 36864);
  float s = 0.f, s2 = 0.f;
#pragma unroll
  for (int i = 0; i < 36; ++i) {
    float4 v = src[i * 256 + threadIdx.x];
    s += v.x + v.y + v.z + v.w;
    s2 += v.x * v.x + v.y * v.y + v.z * v.z + v.w * v.w;
  }
#pragma unroll
  for (int off = 1; off < 64; off <<= 1) {
    s += __shfl_xor(s, off);
    s2 += __shfl_xor(s2, off);
  }
  __shared__ float red[8];
  const int wid = threadIdx.x >> 6;
  if ((threadIdx.x & 63) == 0) { red[wid] = s; red[wid + 4] = s2; }
  __syncthreads();
  if (threadIdx.x == 0) {
    float S = red[0] + red[1] + red[2] + red[3];
    float S2 = red[4] + red[5] + red[6] + red[7];
    float mu = S * (1.f / 36864.f);
    float var = S2 * (1.f / 36864.f) - mu * mu;
    stats[bg * 2] = mu;
    stats[bg * 2 + 1] = rsqrtf(var + 1e-5f);
  }
}

// ------- GN normalize + transpose (b,c,s)->(b,s,c), fp32 -> bf16 ----------
__global__ __launch_bounds__(256) void gn_norm_t_kernel(
    const float* __restrict__ x, const float* __restrict__ gamma,
    const float* __restrict__ beta, const float* __restrict__ stats,
    unsigned short* __restrict__ xn) {
  __shared__ float tile[64][68];
  const int s0 = blockIdx.x * 64, c0 = blockIdx.y * 64, b = blockIdx.z;
  const int tid = threadIdx.x;
  {
    const int cl = tid >> 2, sc = (tid & 3) * 16;
    const float* src = x + ((size_t)b * C_DIM + c0 + cl) * S_LEN + s0 + sc;
#pragma unroll
    for (int i = 0; i < 4; ++i)
      *(float4*)&tile[cl][sc + i * 4] = *(const float4*)(src + i * 4);
  }
  __syncthreads();
  const int sl = tid >> 2, cc = (tid & 3) * 16;
  const int g = (c0 + cc) >> 4;
  const float mu = stats[((size_t)b * 32 + g) * 2];
  const float rs = stats[((size_t)b * 32 + g) * 2 + 1];
  u16x8 o0, o1;
#pragma unroll
  for (int j = 0; j < 8; ++j) {
    const int c = c0 + cc + j;
    o0[j] = bf16u((tile[cc + j][sl] - mu) * rs * gamma[c] + beta[c]);
  }
#pragma unroll
  for (int j = 0; j < 8; ++j) {
    const int c = c0 + cc + 8 + j;
    o1[j] = bf16u((tile[cc + 8 + j][sl] - mu) * rs * gamma[c] + beta[c]);
  }
  unsigned short* dst = xn + ((size_t)b * S_LEN + s0 + sl) * C_DIM + c0 + cc;
  *(u16x8*)dst = o0;
  *(u16x8*)(dst + 8) = o1;
}

// --------- weight transpose: w (K,N) fp32 -> wT (N,K) bf16 -----------------
__global__ __launch_bounds__(256) void wt_kernel(const float* __restrict__ w,
                                                 unsigned short* __restrict__ wT,
                                                 int N, int K) {
  __shared__ float tile[64][68];
  const int n0 = blockIdx.x * 64, k0 = blockIdx.y * 64;
  const int tid = threadIdx.x;
  {
    const int kl = tid >> 2, nc = (tid & 3) * 16;
    const float* src = w + (size_t)(k0 + kl) * N + n0 + nc;
#pragma unroll
    for (int i = 0; i < 4; ++i)
      *(float4*)&tile[kl][nc + i * 4] = *(const float4*)(src + i * 4);
  }
  __syncthreads();
  const int nl = tid >> 2, kc = (tid & 3) * 16;
  u16x8 o0, o1;
#pragma unroll
  for (int j = 0; j < 8; ++j) o0[j] = bf16u(tile[kc + j][nl]);
#pragma unroll
  for (int j = 0; j < 8; ++j) o1[j] = bf16u(tile[kc + 8 + j][nl]);
  unsigned short* dst = wT + (size_t)(n0 + nl) * K + k0 + kc;
  *(u16x8*)dst = o0;
  *(u16x8*)(dst + 8) = o1;
}

// ------------- shared 128x128 GEMM mainloop (A:(M,K) B:(N,K), bf16) --------
__device__ __forceinline__ void gemm128_core(const unsigned short* __restrict__ A,
                                             const unsigned short* __restrict__ B,
                                             int K, int m0, int n0, short* lds_a,
                                             short* lds_b, f32x4 (&acc)[4][4]) {
  const int tid = threadIdx.x;
  const int lane = tid & 63, wid = tid >> 6;
  const int wr = wid >> 1, wc = wid & 1;
  const f32x4 fzero = {0.f, 0.f, 0.f, 0.f};
#pragma unroll
  for (int i = 0; i < 4; ++i)
#pragma unroll
    for (int j = 0; j < 4; ++j) acc[i][j] = fzero;
  const int lrow = lane >> 3;
  const int lcol = (lane & 7) * 8;
  for (int kt = 0; kt < K; kt += 64) {
#pragma unroll
    for (int i = 0; i < 4; ++i) {
      const int r0 = (wid * 4 + i) * 8;
      load_lds16((const void*)(A + (size_t)(m0 + r0 + lrow) * K + kt + lcol), lds_a + r0 * 64);
      load_lds16((const void*)(B + (size_t)(n0 + r0 + lrow) * K + kt + lcol), lds_b + r0 * 64);
    }
    __syncthreads();
#pragma unroll
    for (int ks = 0; ks < 2; ++ks) {
      bf16x8 af[4], bfr[4];
#pragma unroll
      for (int mf = 0; mf < 4; ++mf)
        af[mf] = *(const bf16x8*)(lds_a + ((wr * 64 + mf * 16 + (lane & 15)) * 64 +
                                           ks * 32 + (lane >> 4) * 8));
#pragma unroll
      for (int nf = 0; nf < 4; ++nf)
        bfr[nf] = *(const bf16x8*)(lds_b + ((wc * 64 + nf * 16 + (lane & 15)) * 64 +
                                            ks * 32 + (lane >> 4) * 8));
#pragma unroll
      for (int mf = 0; mf < 4; ++mf)
#pragma unroll
        for (int nf = 0; nf < 4; ++nf)
          acc[mf][nf] =
              __builtin_amdgcn_mfma_f32_16x16x32_bf16(af[mf], bfr[nf], acc[mf][nf], 0, 0, 0);
    }
    __syncthreads();
  }
}

// --------------- QKV GEMM: scatter to Q(scaled)/K (bh,s,64), Vt (bh,64,s) --
__global__ __launch_bounds__(256) void qkv_gemm_kernel(
    const unsigned short* __restrict__ xn, const unsigned short* __restrict__ wT,
    const float* __restrict__ bq, unsigned short* __restrict__ Qb,
    unsigned short* __restrict__ Kb, unsigned short* __restrict__ Vt) {
  __shared__ short lds_a[128 * 64];
  __shared__ short lds_b[128 * 64];
  const int b = blockIdx.z;
  const int m0 = blockIdx.x * 128, n0 = blockIdx.y * 128;
  f32x4 acc[4][4];
  gemm128_core(xn + (size_t)b * S_LEN * C_DIM, wT, C_DIM, m0, n0, lds_a, lds_b, acc);
  const int lane = threadIdx.x & 63, wid = threadIdx.x >> 6;
  const int wr = wid >> 1, wc = wid & 1;
#pragma unroll
  for (int mf = 0; mf < 4; ++mf) {
#pragma unroll
    for (int nf = 0; nf < 4; ++nf) {
      const int n = n0 + wc * 64 + nf * 16 + (lane & 15);
      const int part = n >> 9;
      const int h = (n >> 6) & 7;
      const int d = n & 63;
      const float bias = bq[n];
      const int m = m0 + wr * 64 + mf * 16 + (lane >> 4) * 4;
      if (part == 2) {
        u16x4 pk;
#pragma unroll
        for (int r = 0; r < 4; ++r) pk[r] = bf16u(acc[mf][nf][r] + bias);
        *(u16x4*)(Vt + ((size_t)(b * NH + h) * HD + d) * S_LEN + m) = pk;
      } else {
        unsigned short* dst = part == 0 ? Qb : Kb;
        const float sc = part == 0 ? 0.18033688011112042f : 1.0f;  // 0.125*log2(e)
#pragma unroll
        for (int r = 0; r < 4; ++r)
          dst[((size_t)(b * NH + h) * S_LEN + m + r) * HD + d] =
              bf16u((acc[mf][nf][r] + bias) * sc);
      }
    }
  }
}

// ----------------------------- flash attention (split-K) -------------------
// Block = 256 thr = 2 q-waves x 2 k-split waves. Each wave: 32 q-rows, 1152
// keys (36 x 32-key tiles). l computed via ones-MFMA on the bf16 P actually
// used in PV (denominator-consistent: absmax 0.0625 evidence from R3/R4).
#define QBLK 64
__global__ __launch_bounds__(256, 4) void attn_kernel(const unsigned short* __restrict__ Q,
                                                      const unsigned short* __restrict__ K,
                                                      const unsigned short* __restrict__ Vt,
                                                      unsigned short* __restrict__ O) {
  __shared__ __align__(16) char smem[32768];
  const int tid = threadIdx.x;
  const int w = tid >> 6, l = tid & 63;
  const int l31 = l & 31, hi = l >> 5;
  const int ks = w & 1, qw = w >> 1;
  // XCD-aware remap: each XCD gets 4 (b,h) x 36 q-tiles -> KV L2-resident.
  const int L = blockIdx.y * 36 + blockIdx.x;
  const int xcd = L & 7, j = L >> 3;
  const int bh = xcd * 4 + j / 36;
  const int qt = j % 36;
  const int b = bh >> 3, h = bh & 7;
  const int q0 = qt * QBLK;

  const char* gQ = (const char*)Q + (size_t)bh * S_LEN * 128;
  const char* gK = (const char*)K + (size_t)bh * S_LEN * 128;
  const char* gV = (const char*)Vt + (size_t)bh * HD * (S_LEN * 2);

  // ---- Q direct to regs (issued first so vmcnt(4) waits cover it) ----
  bf16x8 qf[4];
  {
    const char* qp = gQ + (size_t)(q0 + qw * 32 + l31) * 128 + hi * 16;
#pragma unroll
    for (int d4 = 0; d4 < 4; ++d4) qf[d4] = *(const bf16x8*)(qp + d4 * 32);
  }

  // ---- per-thread staging descriptors (4 chunks: K0, V0, K1, V1) ----
  const int sr = tid >> 3, sch = tid & 7;
  const char* pk0;
  const char* pv0;
  {
    pk0 = gK + (size_t)sr * 128 + ((sch ^ (sr & 7)) << 4);
    const int co = sch ^ (sr & 7);
    const int vd = 2 * sr + (co >> 2), slot = co & 3;
    pv0 = gV + (size_t)vd * (S_LEN * 2) + slot * 16;
  }
  const char* pk1 = pk0 + 1152 * 128;
  const char* pv1 = pv0 + 1152 * 2;

  auto stage = [&](int dbuf) {
    char* base = smem + dbuf * 8192 + tid * 16;
    load_lds16((const void*)pk0, base);
    load_lds16((const void*)pv0, base + 4096);
    load_lds16((const void*)pk1, base + 16384);
    load_lds16((const void*)pv1, base + 16384 + 4096);
    pk0 += 4096; pv0 += 64; pk1 += 4096; pv1 += 64;
  };

  stage(0);  // tile 0

  const u16x8 onesu = {0x3F80, 0x3F80, 0x3F80, 0x3F80, 0x3F80, 0x3F80, 0x3F80, 0x3F80};
  const bf16x8 onesf = __builtin_bit_cast(bf16x8, onesu);
  f32x16 z16;
#pragma unroll
  for (int i = 0; i < 16; ++i) z16[i] = 0.f;

  float m_run = -1e30f, lsum = 0.f;
  f32x16 oac0, oac1;
#pragma unroll
  for (int i = 0; i < 16; ++i) { oac0[i] = 0.f; oac1[i] = 0.f; }

  for (int kt = 0; kt < 36; ++kt) {
    if (kt < 35) {
      stage((kt + 1) & 1);
      asm volatile("s_waitcnt vmcnt(4)" ::: "memory");
    } else {
      asm volatile("s_waitcnt vmcnt(0)" ::: "memory");
    }
    __builtin_amdgcn_s_barrier();

    const char* kreg = smem + ks * 16384 + (kt & 1) * 8192;
    const char* vreg = kreg + 4096;

    // ---- S^T = K · Q^T ----
    f32x16 st;
#pragma unroll
    for (int i = 0; i < 16; ++i) st[i] = 0.f;
    {
      const int ksw = l31 & 7;
#pragma unroll
      for (int d4 = 0; d4 < 4; ++d4) {
        bf16x8 kf = *(const bf16x8*)(kreg + l31 * 128 + (((d4 * 2 + hi) ^ ksw) << 4));
        st = __builtin_amdgcn_mfma_f32_32x32x16_bf16(kf, qf[d4], st, 0, 0, 0);
      }
    }
    // ---- online softmax max (R2-exact) ----
    float t8[8];
#pragma unroll
    for (int i = 0; i < 8; ++i) t8[i] = fmaxf(st[2 * i], st[2 * i + 1]);
#pragma unroll
    for (int i = 0; i < 4; ++i) t8[i] = fmaxf(t8[i], t8[i + 4]);
    float mt = fmaxf(fmaxf(t8[0], t8[1]), fmaxf(t8[2], t8[3]));
    {
      float mo = mt;
      asm volatile("v_permlane32_swap_b32 %0, %1" : "+v"(mt), "+v"(mo));
      mt = fmaxf(mt, mo);
    }
    if (__any((mt - m_run) > 8.f)) {  // defer-max THR=8 (log2 domain)
      const float mnew = fmaxf(m_run, mt);
      const float corr = exp2f(m_run - mnew);
#pragma unroll
      for (int i = 0; i < 16; ++i) { oac0[i] *= corr; oac1[i] *= corr; }
      lsum *= corr;
      m_run = mnew;
    }
    float p[16];
#pragma unroll
    for (int i = 0; i < 16; ++i) p[i] = exp2f(st[i] - m_run);
    // ---- P -> bf16 B-fragments via cvt_pk + permlane32_swap ----
    unsigned int wv[8];
#pragma unroll
    for (int jj = 0; jj < 8; ++jj)
      asm("v_cvt_pk_bf16_f32 %0, %1, %2" : "=v"(wv[jj]) : "v"(p[2 * jj]), "v"(p[2 * jj + 1]));
    asm volatile("v_permlane32_swap_b32 %0, %1" : "+v"(wv[0]), "+v"(wv[2]));
    asm volatile("v_permlane32_swap_b32 %0, %1" : "+v"(wv[1]), "+v"(wv[3]));
    asm volatile("v_permlane32_swap_b32 %0, %1" : "+v"(wv[4]), "+v"(wv[6]));
    asm volatile("v_permlane32_swap_b32 %0, %1" : "+v"(wv[5]), "+v"(wv[7]));
    u32x4 pw0 = {wv[0], wv[1], wv[2], wv[3]};
    u32x4 pw1 = {wv[4], wv[5], wv[6], wv[7]};
    bf16x8 pf0 = __builtin_bit_cast(bf16x8, pw0);
    bf16x8 pf1 = __builtin_bit_cast(bf16x8, pw1);
    // ---- l from the bf16 P actually used in PV (transient ones-MFMA) ----
    {
      f32x16 tmp = __builtin_amdgcn_mfma_f32_32x32x16_bf16(onesf, pf0, z16, 0, 0, 0);
      tmp = __builtin_amdgcn_mfma_f32_32x32x16_bf16(onesf, pf1, tmp, 0, 0, 0);
      lsum += tmp[0];
    }
    // ---- O^T += V^T · P^T ----
    {
      const int vr = l31 >> 1;
      const int c0 = ((l31 & 1) * 4 + hi) ^ (vr & 7);
      const int c1 = ((l31 & 1) * 4 + 2 + hi) ^ (vr & 7);
      bf16x8 vf0 = *(const bf16x8*)(vreg + vr * 128 + (c0 << 4));
      oac0 = __builtin_amdgcn_mfma_f32_32x32x16_bf16(vf0, pf0, oac0, 0, 0, 0);
      bf16x8 vf1 = *(const bf16x8*)(vreg + vr * 128 + (c1 << 4));
      oac0 = __builtin_amdgcn_mfma_f32_32x32x16_bf16(vf1, pf1, oac0, 0, 0, 0);
    }
    {
      const int vr = 16 + (l31 >> 1);
      const int c0 = ((l31 & 1) * 4 + hi) ^ (vr & 7);
      const int c1 = ((l31 & 1) * 4 + 2 + hi) ^ (vr & 7);
      bf16x8 vf0 = *(const bf16x8*)(vreg + vr * 128 + (c0 << 4));
      oac1 = __builtin_amdgcn_mfma_f32_32x32x16_bf16(vf0, pf0, oac1, 0, 0, 0);
      bf16x8 vf1 = *(const bf16x8*)(vreg + vr * 128 + (c1 << 4));
      oac1 = __builtin_amdgcn_mfma_f32_32x32x16_bf16(vf1, pf1, oac1, 0, 0, 0);
    }
    __builtin_amdgcn_s_barrier();
  }

  // ---- flash merge of the two k-split halves + coalesced store ----
  __syncthreads();
  float* fl = (float*)smem;          // [0..127]=m, [128..255]=l, [256..319]=inv
  float* obuf = fl + 512;            // [64][68] fp32
  if (hi == 0) {
    fl[w * 32 + l31] = m_run;
    fl[128 + w * 32 + l31] = lsum;
  }
  __syncthreads();
  const float pm = fl[(w ^ 1) * 32 + l31];
  const float pl = fl[128 + (w ^ 1) * 32 + l31];
  const float mM = fmaxf(m_run, pm);
  const float sOwn = exp2f(m_run - mM);
  const float newl = lsum * sOwn + pl * exp2f(pm - mM);
  const int q = qw * 32 + l31;
  if (ks == 0) {
    if (hi == 0) fl[256 + q] = 1.f / newl;
#pragma unroll
    for (int g = 0; g < 4; ++g) {
      float4 v0 = {oac0[g * 4] * sOwn, oac0[g * 4 + 1] * sOwn, oac0[g * 4 + 2] * sOwn,
                   oac0[g * 4 + 3] * sOwn};
      *(float4*)&obuf[q * 68 + g * 8 + hi * 4] = v0;
      float4 v1 = {oac1[g * 4] * sOwn, oac1[g * 4 + 1] * sOwn, oac1[g * 4 + 2] * sOwn,
                   oac1[g * 4 + 3] * sOwn};
      *(float4*)&obuf[q * 68 + 32 + g * 8 + hi * 4] = v1;
    }
  }
  __syncthreads();
  if (ks == 1) {
#pragma unroll
    for (int g = 0; g < 4; ++g) {
      float4 v0 = *(const float4*)&obuf[q * 68 + g * 8 + hi * 4];
      v0.x += oac0[g * 4] * sOwn; v0.y += oac0[g * 4 + 1] * sOwn;
      v0.z += oac0[g * 4 + 2] * sOwn; v0.w += oac0[g * 4 + 3] * sOwn;
      *(float4*)&obuf[q * 68 + g * 8 + hi * 4] = v0;
      float4 v1 = *(const float4*)&obuf[q * 68 + 32 + g * 8 + hi * 4];
      v1.x += oac1[g * 4] * sOwn; v1.y += oac1[g * 4 + 1] * sOwn;
      v1.z += oac1[g * 4 + 2] * sOwn; v1.w += oac1[g * 4 + 3] * sOwn;
      *(float4*)&obuf[q * 68 + 32 + g * 8 + hi * 4] = v1;
    }
  }
  __syncthreads();
#pragma unroll
  for (int i = 0; i < 2; ++i) {
    const int c = i * 256 + tid;
    const int r = c >> 3, ch = c & 7;
    const float invr = fl[256 + r];
    u16x8 o;
#pragma unroll
    for (int jj = 0; jj < 8; ++jj) o[jj] = bf16u(obuf[r * 68 + ch * 8 + jj] * invr);
    *(u16x8*)(O + ((size_t)b * S_LEN + q0 + r) * C_DIM + h * HD + ch * 8) = o;
  }
}

// ------------- proj GEMM (M=c_out, N=s) + bias + residual, fp32 out --------
__global__ __launch_bounds__(256) void proj_gemm_kernel(
    const unsigned short* __restrict__ wT, const unsigned short* __restrict__ ao,
    const float* __restrict__ bp, const float* __restrict__ x, float* __restrict__ out) {
  __shared__ short lds_a[128 * 64];
  __shared__ short lds_b[128 * 64];
  const int b = blockIdx.z;
  const int m0 = blockIdx.x * 128, n0 = blockIdx.y * 128;
  f32x4 acc[4][4];
  gemm128_core(wT, ao + (size_t)b * S_LEN * C_DIM, C_DIM, m0, n0, lds_a, lds_b, acc);
  const int lane = threadIdx.x & 63, wid = threadIdx.x >> 6;
  const int wr = wid >> 1, wc = wid & 1;
#pragma unroll
  for (int mf = 0; mf < 4; ++mf) {
#pragma unroll
    for (int nf = 0; nf < 4; ++nf) {
      const int n = n0 + wc * 64 + nf * 16 + (lane & 15);
#pragma unroll
      for (int r = 0; r < 4; ++r) {
        const int m = m0 + wr * 64 + mf * 16 + (lane >> 4) * 4 + r;
        const size_t idx = ((size_t)b * C_DIM + m) * S_LEN + n;
        out[idx] = x[idx] + acc[mf][nf][r] + bp[m];
      }
    }
  }
}

extern "C" void kernel_launch(void* const* d_in, const int* in_sizes, int n_in,
                              void* d_out, int out_size, void* d_ws, size_t ws_size,
                              hipStream_t stream) {
  const float* x = (const float*)d_in[0];
  const float* gamma = (const float*)d_in[1];
  const float* beta = (const float*)d_in[2];
  const float* w_qkv = (const float*)d_in[3];
  const float* b_qkv = (const float*)d_in[4];
  const float* w_proj = (const float*)d_in[5];
  const float* b_proj = (const float*)d_in[6];
  float* out = (float*)d_out;

  char* ws = (char*)d_ws;
  float* stats = (float*)ws;                                   // 1 KB
  unsigned short* xn = (unsigned short*)(ws + 1024);           // 9437184 B
  unsigned short* wqkvT = (unsigned short*)(ws + 9438208);     // 1572864 B
  unsigned short* wprojT = (unsigned short*)(ws + 11011072);   // 524288 B
  unsigned short* Qb = (unsigned short*)(ws + 11535360);       // 9437184 B
  unsigned short* Kb = (unsigned short*)(ws + 20972544);       // 9437184 B
  unsigned short* Vt = (unsigned short*)(ws + 30409728);       // 9437184 B
  unsigned short* ao = (unsigned short*)(ws + 39846912);       // 9437184 B

  hipLaunchKernelGGL(gn_stats_kernel, dim3(128), dim3(256), 0, stream, x, stats);
  hipLaunchKernelGGL(wt_kernel, dim3(24, 8), dim3(256), 0, stream, w_qkv, wqkvT, 3 * C_DIM, C_DIM);
  hipLaunchKernelGGL(wt_kernel, dim3(8, 8), dim3(256), 0, stream, w_proj, wprojT, C_DIM, C_DIM);
  hipLaunchKernelGGL(gn_norm_t_kernel, dim3(36, 8, 4), dim3(256), 0, stream, x, gamma, beta, stats, xn);
  hipLaunchKernelGGL(qkv_gemm_kernel, dim3(18, 12, 4), dim3(256), 0, stream, xn, wqkvT, b_qkv, Qb, Kb, Vt);
  hipLaunchKernelGGL(attn_kernel, dim3(36, 32), dim3(256), 0, stream, Qb, Kb, Vt, ao);
  hipLaunchKernelGGL(proj_gemm_kernel, dim3(4, 18, 4), dim3(256), 0, stream, wprojT, ao, b_proj, x, out);
}